// Round 1
// baseline (348.039 us; speedup 1.0000x reference)
//
#include <hip/hip_runtime.h>

#define BATCH 16

// ---------------- d-step: D=4 MPS over inner (H-2)x(H-2) region, in place ----
__global__ __launch_bounds__(256) void d_kernel(
    float* __restrict__ h, const float* __restrict__ A,
    const float* __restrict__ v, const float* __restrict__ w,
    int H, int nh) {
  int g = blockIdx.x * blockDim.x + threadIdx.x;
  int total = nh * nh * BATCH;
  if (g >= total) return;
  int b = g & 15;
  int p = g >> 4;
  int pi = p / nh, pj = p % nh;
  float* xb = h + (size_t)b * H * H;
  int r0 = 1 + 2 * pi, c0 = 1 + 2 * pj;
  float t[4];
  t[0] = xb[r0 * H + c0];
  t[1] = xb[r0 * H + c0 + 1];
  t[2] = xb[(r0 + 1) * H + c0];
  t[3] = xb[(r0 + 1) * H + c0 + 1];
  const float* Ap = A + (size_t)p * 128;  // [s][f][4][4]
  float vec[4];
#pragma unroll
  for (int i = 0; i < 4; i++) vec[i] = v[p * 4 + i];
#pragma unroll
  for (int s = 0; s < 4; s++) {
    float ts = t[s], us = 1.0f - ts;
    const float* A0 = Ap + s * 32;
    const float* A1 = A0 + 16;
    float vn[4] = {0.f, 0.f, 0.f, 0.f};
#pragma unroll
    for (int i = 0; i < 4; i++) {
      float vi = vec[i];
#pragma unroll
      for (int j = 0; j < 4; j++) {
        float m = ts * A0[i * 4 + j] + us * A1[i * 4 + j];
        vn[j] += vi * m;
      }
    }
#pragma unroll
    for (int j = 0; j < 4; j++) vec[j] = vn[j];
  }
  const float* wp = w + p * 16;  // [4][4]
  float y[4];
#pragma unroll
  for (int o = 0; o < 4; o++) {
    float acc = 0.f;
#pragma unroll
    for (int i = 0; i < 4; i++) acc += vec[i] * wp[i * 4 + o];
    y[o] = fmaxf(acc, 0.0f);
  }
  xb[r0 * H + c0] = y[0];
  xb[r0 * H + c0 + 1] = y[1];
  xb[(r0 + 1) * H + c0] = y[2];
  xb[(r0 + 1) * H + c0 + 1] = y[3];
}

// ---------------- i-step: D=16 MPS over full HxH -> (H/2)x(H/2) --------------
__global__ __launch_bounds__(256) void i_kernel(
    const float* __restrict__ h, float* __restrict__ hn,
    const float* __restrict__ A, const float* __restrict__ v,
    const float* __restrict__ w, int H) {
  int W2 = H >> 1;
  int g = blockIdx.x * blockDim.x + threadIdx.x;
  int total = W2 * W2 * BATCH;
  if (g >= total) return;
  int b = g & 15;
  int p = g >> 4;
  int pi = p / W2, pj = p % W2;
  const float* xb = h + (size_t)b * H * H;
  int r0 = 2 * pi, c0 = 2 * pj;
  float t[4];
  t[0] = xb[r0 * H + c0];
  t[1] = xb[r0 * H + c0 + 1];
  t[2] = xb[(r0 + 1) * H + c0];
  t[3] = xb[(r0 + 1) * H + c0 + 1];
  const float* Ap = A + (size_t)p * 2048;  // [s][f][16][16]
  float vec[16];
#pragma unroll
  for (int i = 0; i < 16; i++) vec[i] = v[p * 16 + i];
#pragma unroll
  for (int s = 0; s < 4; s++) {
    float ts = t[s], us = 1.0f - ts;
    const float4* A0 = (const float4*)(Ap + s * 512);
    const float4* A1 = (const float4*)(Ap + s * 512 + 256);
    float vn[16];
#pragma unroll
    for (int j = 0; j < 16; j++) vn[j] = 0.0f;
#pragma unroll
    for (int i = 0; i < 16; i++) {
      float vi = vec[i];
#pragma unroll
      for (int q = 0; q < 4; q++) {
        float4 a0 = A0[i * 4 + q];
        float4 a1 = A1[i * 4 + q];
        vn[q * 4 + 0] += vi * (ts * a0.x + us * a1.x);
        vn[q * 4 + 1] += vi * (ts * a0.y + us * a1.y);
        vn[q * 4 + 2] += vi * (ts * a0.z + us * a1.z);
        vn[q * 4 + 3] += vi * (ts * a0.w + us * a1.w);
      }
    }
#pragma unroll
    for (int j = 0; j < 16; j++) vec[j] = vn[j];
  }
  float acc = 0.f;
#pragma unroll
  for (int i = 0; i < 16; i++) acc += vec[i] * w[p * 16 + i];
  hn[(size_t)b * W2 * W2 + pi * W2 + pj] = fmaxf(acc, 0.0f);
}

// ---------------- final head: (16,2,2) -> (16,10) ----------------------------
__global__ void final_kernel(const float* __restrict__ h6,
                             const float* __restrict__ A,
                             const float* __restrict__ v,
                             const float* __restrict__ w,
                             float* __restrict__ out) {
  int b = threadIdx.x;
  if (b >= BATCH) return;
  float t[4];
#pragma unroll
  for (int s = 0; s < 4; s++) t[s] = h6[b * 4 + s];
  float vec[16];
#pragma unroll
  for (int i = 0; i < 16; i++) vec[i] = v[i];
#pragma unroll
  for (int s = 0; s < 4; s++) {
    float ts = t[s], us = 1.0f - ts;
    const float* A0 = A + s * 512;
    const float* A1 = A0 + 256;
    float vn[16];
#pragma unroll
    for (int j = 0; j < 16; j++) vn[j] = 0.0f;
#pragma unroll
    for (int i = 0; i < 16; i++) {
      float vi = vec[i];
#pragma unroll
      for (int j = 0; j < 16; j++) {
        float m = ts * A0[i * 16 + j] + us * A1[i * 16 + j];
        vn[j] += vi * m;
      }
    }
#pragma unroll
    for (int j = 0; j < 16; j++) vec[j] = vn[j];
  }
#pragma unroll
  for (int o = 0; o < 10; o++) {
    float acc = 0.f;
#pragma unroll
    for (int i = 0; i < 16; i++) acc += vec[i] * w[i * 10 + o];
    out[b * 10 + o] = fmaxf(acc, 0.0f);
  }
}

extern "C" void kernel_launch(void* const* d_in, const int* in_sizes, int n_in,
                              void* d_out, int out_size, void* d_ws, size_t ws_size,
                              hipStream_t stream) {
  const float* x = (const float*)d_in[0];
  float* ws = (float*)d_ws;

  // h pyramid in workspace
  hipMemcpyAsync(ws, x, (size_t)BATCH * 128 * 128 * sizeof(float),
                 hipMemcpyDeviceToDevice, stream);

  int H = 128;
  size_t hoff = 0;
  for (int l = 0; l < 6; l++) {
    const float* dA = (const float*)d_in[1 + 6 * l + 0];
    const float* dv = (const float*)d_in[1 + 6 * l + 1];
    const float* dw = (const float*)d_in[1 + 6 * l + 2];
    const float* iA = (const float*)d_in[1 + 6 * l + 3];
    const float* iv = (const float*)d_in[1 + 6 * l + 4];
    const float* iw = (const float*)d_in[1 + 6 * l + 5];

    int nh = (H - 2) / 2;
    int totd = nh * nh * BATCH;
    d_kernel<<<(totd + 255) / 256, 256, 0, stream>>>(ws + hoff, dA, dv, dw, H, nh);

    int W2 = H / 2;
    size_t hoff_next = hoff + (size_t)BATCH * H * H;
    int toti = W2 * W2 * BATCH;
    i_kernel<<<(toti + 255) / 256, 256, 0, stream>>>(ws + hoff, ws + hoff_next,
                                                     iA, iv, iw, H);
    hoff = hoff_next;
    H = W2;
  }

  final_kernel<<<1, 64, 0, stream>>>(ws + hoff, (const float*)d_in[37],
                                     (const float*)d_in[38],
                                     (const float*)d_in[39], (float*)d_out);
}